// Round 8
// baseline (3832.098 us; speedup 1.0000x reference)
//
#include <hip/hip_runtime.h>

#define TT 1024
#define BB 64
#define FF 256
#define HH 512

// ---------------------------------------------------------------------------
// Kernel 1: i_n = x @ W_ih^T + b_ih  -> io (= d_out), overwritten in-place by
// the recurrence with h_t.  (unchanged)
// ---------------------------------------------------------------------------
__global__ __launch_bounds__(256) void in_gemm(
    const float* __restrict__ x, const float* __restrict__ Wih,
    const float* __restrict__ bih, float* __restrict__ io)
{
    __shared__ float xs[32][68];
    __shared__ float wst[64][68];

    const int bid = blockIdx.x;
    const int rb = bid >> 3, cb = bid & 7;
    const int m0 = rb * 32, n0 = cb * 64;
    const int t  = threadIdx.x;
    const int ti = t >> 4, tj = t & 15;

    float acc[2][4] = {{0.f,0.f,0.f,0.f},{0.f,0.f,0.f,0.f}};

    for (int k0 = 0; k0 < FF; k0 += 64) {
        {
            int flat = t * 8;
            int row = flat >> 6, col = flat & 63;
            const float* src = &x[(size_t)(m0 + row) * FF + k0 + col];
            float4 a = *(const float4*)&src[0];
            float4 b = *(const float4*)&src[4];
            *(float4*)&xs[row][col]     = a;
            *(float4*)&xs[row][col + 4] = b;
        }
        {
            int j  = t >> 2;
            int kk = (t & 3) * 16;
            const float* src = &Wih[(size_t)(n0 + j) * FF + k0 + kk];
            #pragma unroll
            for (int q = 0; q < 4; ++q) {
                float4 v = *(const float4*)&src[q * 4];
                wst[kk + q*4 + 0][j] = v.x;
                wst[kk + q*4 + 1][j] = v.y;
                wst[kk + q*4 + 2][j] = v.z;
                wst[kk + q*4 + 3][j] = v.w;
            }
        }
        __syncthreads();
        #pragma unroll
        for (int k = 0; k < 64; k += 4) {
            float4 xa = *(const float4*)&xs[ti][k];
            float4 xb = *(const float4*)&xs[ti + 16][k];
            #pragma unroll
            for (int q = 0; q < 4; ++q) {
                float4 wv = *(const float4*)&wst[k + q][tj * 4];
                float xav = (&xa.x)[q], xbv = (&xb.x)[q];
                acc[0][0] = fmaf(xav, wv.x, acc[0][0]);
                acc[0][1] = fmaf(xav, wv.y, acc[0][1]);
                acc[0][2] = fmaf(xav, wv.z, acc[0][2]);
                acc[0][3] = fmaf(xav, wv.w, acc[0][3]);
                acc[1][0] = fmaf(xbv, wv.x, acc[1][0]);
                acc[1][1] = fmaf(xbv, wv.y, acc[1][1]);
                acc[1][2] = fmaf(xbv, wv.z, acc[1][2]);
                acc[1][3] = fmaf(xbv, wv.w, acc[1][3]);
            }
        }
        __syncthreads();
    }

    float4 bv = *(const float4*)&bih[n0 + tj * 4];
    float4 r0 = make_float4(acc[0][0]+bv.x, acc[0][1]+bv.y, acc[0][2]+bv.z, acc[0][3]+bv.w);
    float4 r1 = make_float4(acc[1][0]+bv.x, acc[1][1]+bv.y, acc[1][2]+bv.z, acc[1][3]+bv.w);
    *(float4*)&io[(size_t)(m0 + ti)      * HH + n0 + tj * 4] = r0;
    *(float4*)&io[(size_t)(m0 + ti + 16) * HH + n0 + tj * 4] = r1;
}

// ---------------------------------------------------------------------------
// Kernel 2: ROUND-8 — 4-chain software pipeline.
//
// Rounds 2-7: protocol surgery moved time <=12% each; step stayed ~5900 cy
// vs ~2600 cy of issue. Diagnosis: ONE serial chain per group -- publish
// visibility, poll, FMA wall, single-wave epilogue all back-to-back.
//
// Restructure: 16 groups x 4 batches x 16 WGs (256 WGs, 1/CU enforced by a
// 90 KB LDS pad -- also guarantees co-residency for the spin protocol).
// Each WG owns h-rows [32*sp, 32*sp+32) (f and n) for its 4 batches.
// Step = 4 phases; phase b: poll h_b (epoch-in-mantissa data poll, r7) ->
// 64 FMA/thread -> sync -> WAVE b alone reduces + gates + publishes batch b
// while other waves start phase b+1. Batch b's publish->re-poll slack is
// 3 phases (~1500 cy) => L3 RTT off the critical path.
// Epilogue: __expf-based sigmoid/tanh (native v_exp, correct saturation);
// i_n prefetched one full step ahead into registers.
// Per-thread: Wf[32]+Wn[32] (row l&31, 32-wide k-subslice, half l>>5).
// Reduce: 16 partials (8 waves x 2 halves) via LDS, parity-double-buffered.
// ---------------------------------------------------------------------------
#define P8(A,i) "+v"(A[(i)+0]), "+v"(A[(i)+1]), "+v"(A[(i)+2]), "+v"(A[(i)+3]), \
                "+v"(A[(i)+4]), "+v"(A[(i)+5]), "+v"(A[(i)+6]), "+v"(A[(i)+7])

__global__ __launch_bounds__(512, 2) void mgu_rec(
    const float* __restrict__ Whh, const float* __restrict__ bhh,
    float* __restrict__ io, float* __restrict__ hbuf)
{
    const int bid = blockIdx.x;
    const int sp  = bid >> 4;      // row slice 0..15 (32 h-rows)
    const int g   = bid & 15;      // batch group 0..15
    const int c0  = g * 4;         // first of 4 batches
    const int tid = threadIdx.x;
    const int w   = tid >> 6;      // wave 0..7 -> 64-wide k-slice
    const int l   = tid & 63;      // lane
    const int r   = l & 31;        // row within slice (2 lanes/row)
    const int hf  = l >> 5;        // k-half within wave slice

    __shared__ float hst[HH];               // staged h, wave-private 64-slices (2 KB)
    __shared__ float red[2][8][2][2][32];   // [parity][wave][half][gate][row] (16 KB)
    __shared__ float lds_pad[18432];        // 72 KB: total 90 KB > 80 KB
                                            // => hardware cannot co-schedule a
                                            // 2nd WG on the CU (1 WG/CU exact)
    if (tid == 0) {                         // volatile touch: keep allocation
        volatile float* vp = lds_pad;
        vp[0] = 0.f;
    }

    // --- persistent W: row 32*sp + r, k-cols [64w + 32*hf, +32) ---
    float Wf[32], Wn[32];
    {
        const int row = 32 * sp + r;
        const int kb  = 64 * w + 32 * hf;
        const float* pf = &Whh[(size_t)row * HH + kb];
        const float* pn = &Whh[(size_t)(512 + row) * HH + kb];
        #pragma unroll
        for (int q = 0; q < 8; ++q) {
            float4 a = *(const float4*)&pf[q * 4];
            Wf[q*4+0] = a.x; Wf[q*4+1] = a.y; Wf[q*4+2] = a.z; Wf[q*4+3] = a.w;
            float4 b = *(const float4*)&pn[q * 4];
            Wn[q*4+0] = b.x; Wn[q*4+1] = b.y; Wn[q*4+2] = b.z; Wn[q*4+3] = b.w;
        }
    }
    asm volatile("" : P8(Wf,0),  P8(Wf,8),  P8(Wf,16), P8(Wf,24));
    asm volatile("" : P8(Wn,0),  P8(Wn,8),  P8(Wn,16), P8(Wn,24));

    // epilogue role: wave b (<4), lanes 0..31 handle batch c0+b, row 32*sp+l
    const bool epi = (w < 4) && (l < 32);
    float bfv = 0.f, bnv = 0.f, hprev = 0.f, in_cur = 0.f, in_next = 0.f;
    size_t obase = 0;
    if (epi) {
        bfv = bhh[32 * sp + l];
        bnv = bhh[512 + 32 * sp + l];
        obase = (size_t)(c0 + w) * HH + 32 * sp + l;   // + t*BB*HH per step
        in_next = io[obase];                            // i_n for t=0
    }

    const int kbase = 64 * w + 32 * hf;

    for (int t = 0; t < TT; ++t) {
        // rotate i_n pipeline: use in_cur this step, prefetch t+1 (full-step hiding)
        in_cur = in_next;
        if (epi && t + 1 < TT)
            in_next = io[obase + (size_t)(t + 1) * BB * HH];

        #pragma unroll
        for (int b = 0; b < 4; ++b) {
            const int pr = b & 1;

            // ---- data-poll own k-slice of batch b's h_{t-1} ----
            float v;
            if (t > 0) {
                const int tr = t - 1;
                const unsigned ep = (unsigned)(((tr >> 2) % 3) + 1);
                const float* src = &hbuf[((size_t)(tr & 3) * BB + (c0 + b)) * HH
                                         + 64 * w + l];
                for (;;) {
                    v = __hip_atomic_load(src, __ATOMIC_RELAXED,
                                          __HIP_MEMORY_SCOPE_AGENT);
                    if (__all((int)((__float_as_uint(v) & 3u) == ep))) break;
                }
            } else {
                v = 0.f;
            }
            hst[64 * w + l] = v;           // wave-private slice; no barrier

            // ---- 64 FMA: row r, 32-wide k-subslice, gates f and n ----
            float pf = 0.f, pn = 0.f;
            #pragma unroll
            for (int q = 0; q < 8; ++q) {
                float4 h4 = *(const float4*)&hst[kbase + 4 * q];
                pf = fmaf(Wf[q*4+0], h4.x, pf); pn = fmaf(Wn[q*4+0], h4.x, pn);
                pf = fmaf(Wf[q*4+1], h4.y, pf); pn = fmaf(Wn[q*4+1], h4.y, pn);
                pf = fmaf(Wf[q*4+2], h4.z, pf); pn = fmaf(Wn[q*4+2], h4.z, pn);
                pf = fmaf(Wf[q*4+3], h4.w, pf); pn = fmaf(Wn[q*4+3], h4.w, pn);
            }
            red[pr][w][hf][0][r] = pf;
            red[pr][w][hf][1][r] = pn;

            __syncthreads();

            // ---- epilogue: wave b only; others roll into phase b+1 ----
            if (w == b && l < 32) {
                float fs = 0.f, ns = 0.f;
                #pragma unroll
                for (int i = 0; i < 8; ++i) {
                    fs += red[pr][i][0][0][l] + red[pr][i][1][0][l];
                    ns += red[pr][i][0][1][l] + red[pr][i][1][1][l];
                }
                // sigmoid / tanh via native exp (saturation-safe)
                float fg = __builtin_amdgcn_rcpf(1.f + __expf(-(fs + bfv)));
                float e2 = __expf(2.f * (in_cur + fg * (ns + bnv)));
                float nv = 1.f - 2.f * __builtin_amdgcn_rcpf(e2 + 1.f);
                float hn = nv + (1.f - fg) * (hprev - nv);
                hprev = hn;

                // publish epoch-encoded h (critical path), then harness output
                const unsigned ep = (unsigned)(((t >> 2) % 3) + 1);
                float ev = __uint_as_float((__float_as_uint(hn) & ~3u) | ep);
                float* dst = &hbuf[((size_t)(t & 3) * BB + (c0 + b)) * HH
                                   + 32 * sp + l];
                __hip_atomic_store(dst, ev, __ATOMIC_RELAXED,
                                   __HIP_MEMORY_SCOPE_AGENT);
                io[obase + (size_t)t * BB * HH] = hn;
            }
        }
    }
}

// ---------------------------------------------------------------------------
extern "C" void kernel_launch(void* const* d_in, const int* in_sizes, int n_in,
                              void* d_out, int out_size, void* d_ws, size_t ws_size,
                              hipStream_t stream)
{
    const float* x   = (const float*)d_in[0];
    const float* Wih = (const float*)d_in[1];
    const float* Whh = (const float*)d_in[2];
    const float* bih = (const float*)d_in[3];
    const float* bhh = (const float*)d_in[4];
    float* io = (float*)d_out;

    float* hbuf = (float*)d_ws;   // 4 slots x 64 batches x 512 f32 = 512 KB

    // zero the slot ring: epoch bits 0 never match live epochs {1,2,3};
    // re-runs every launch/replay -> deterministic.
    hipMemsetAsync(d_ws, 0, 4 * BB * HH * 4, stream);

    in_gemm<<<dim3(16384), dim3(256), 0, stream>>>(x, Wih, bih, io);
    mgu_rec<<<dim3(256), dim3(512), 0, stream>>>(Whh, bhh, io, hbuf);
}

// Round 9
// 2050.520 us; speedup vs baseline: 1.8688x; 1.8688x over previous
//
#include <hip/hip_runtime.h>

#define TT 1024
#define BB 64
#define FF 256
#define HH 512

// ---------------------------------------------------------------------------
// Kernel 1: i_n = x @ W_ih^T + b_ih  -> io (= d_out), overwritten in-place by
// the recurrence with h_t.  (unchanged)
// ---------------------------------------------------------------------------
__global__ __launch_bounds__(256) void in_gemm(
    const float* __restrict__ x, const float* __restrict__ Wih,
    const float* __restrict__ bih, float* __restrict__ io)
{
    __shared__ float xs[32][68];
    __shared__ float wst[64][68];

    const int bid = blockIdx.x;
    const int rb = bid >> 3, cb = bid & 7;
    const int m0 = rb * 32, n0 = cb * 64;
    const int t  = threadIdx.x;
    const int ti = t >> 4, tj = t & 15;

    float acc[2][4] = {{0.f,0.f,0.f,0.f},{0.f,0.f,0.f,0.f}};

    for (int k0 = 0; k0 < FF; k0 += 64) {
        {
            int flat = t * 8;
            int row = flat >> 6, col = flat & 63;
            const float* src = &x[(size_t)(m0 + row) * FF + k0 + col];
            float4 a = *(const float4*)&src[0];
            float4 b = *(const float4*)&src[4];
            *(float4*)&xs[row][col]     = a;
            *(float4*)&xs[row][col + 4] = b;
        }
        {
            int j  = t >> 2;
            int kk = (t & 3) * 16;
            const float* src = &Wih[(size_t)(n0 + j) * FF + k0 + kk];
            #pragma unroll
            for (int q = 0; q < 4; ++q) {
                float4 v = *(const float4*)&src[q * 4];
                wst[kk + q*4 + 0][j] = v.x;
                wst[kk + q*4 + 1][j] = v.y;
                wst[kk + q*4 + 2][j] = v.z;
                wst[kk + q*4 + 3][j] = v.w;
            }
        }
        __syncthreads();
        #pragma unroll
        for (int k = 0; k < 64; k += 4) {
            float4 xa = *(const float4*)&xs[ti][k];
            float4 xb = *(const float4*)&xs[ti + 16][k];
            #pragma unroll
            for (int q = 0; q < 4; ++q) {
                float4 wv = *(const float4*)&wst[k + q][tj * 4];
                float xav = (&xa.x)[q], xbv = (&xb.x)[q];
                acc[0][0] = fmaf(xav, wv.x, acc[0][0]);
                acc[0][1] = fmaf(xav, wv.y, acc[0][1]);
                acc[0][2] = fmaf(xav, wv.z, acc[0][2]);
                acc[0][3] = fmaf(xav, wv.w, acc[0][3]);
                acc[1][0] = fmaf(xbv, wv.x, acc[1][0]);
                acc[1][1] = fmaf(xbv, wv.y, acc[1][1]);
                acc[1][2] = fmaf(xbv, wv.z, acc[1][2]);
                acc[1][3] = fmaf(xbv, wv.w, acc[1][3]);
            }
        }
        __syncthreads();
    }

    float4 bv = *(const float4*)&bih[n0 + tj * 4];
    float4 r0 = make_float4(acc[0][0]+bv.x, acc[0][1]+bv.y, acc[0][2]+bv.z, acc[0][3]+bv.w);
    float4 r1 = make_float4(acc[1][0]+bv.x, acc[1][1]+bv.y, acc[1][2]+bv.z, acc[1][3]+bv.w);
    *(float4*)&io[(size_t)(m0 + ti)      * HH + n0 + tj * 4] = r0;
    *(float4*)&io[(size_t)(m0 + ti + 16) * HH + n0 + tj * 4] = r1;
}

// ---------------------------------------------------------------------------
// Kernel 2: ROUND-9 = round-7 structure (32 groups x 2 batches x 8 WGs,
// epoch-in-mantissa data polling, one barrier/step) + three fixes:
//
//  A. FMA loop SOFTWARE-PIPELINED: prefetch next float4 pair while FMA'ing
//     the current one; sched_barrier only every 4 chunks. Round 2-7 had
//     sched_barrier(0) after EVERY chunk, which serialized ds_read latency
//     (~120 cy) into the FMA stream: ~2400 cy instead of ~1100 for the dot
//     phase -- the dominant hidden cost all along (round-8 post-mortem).
//     Bounded hoist (max 4 chunks = 32 h floats live) keeps peak pressure
//     ~190 < 256 VGPR (512-thread WG, 2 waves/SIMD).
//  B. Epilogue split across 2 waves (wave 0 -> batch 0, wave 1 -> batch 1):
//     16-load reduce chain per lane instead of 32, one transcendental
//     chain per lane instead of two. __expf-based gates (native v_exp,
//     saturation-safe; validated in round 8).
//  C. i_n prefetched one full step ahead into registers.
// ---------------------------------------------------------------------------
#define P8(A,i) "+v"(A[(i)+0]), "+v"(A[(i)+1]), "+v"(A[(i)+2]), "+v"(A[(i)+3]), \
                "+v"(A[(i)+4]), "+v"(A[(i)+5]), "+v"(A[(i)+6]), "+v"(A[(i)+7])

__global__ __launch_bounds__(512, 2) void mgu_rec(
    const float* __restrict__ Whh, const float* __restrict__ bhh,
    float* __restrict__ io, float* __restrict__ hbuf)
{
    const int bid = blockIdx.x;
    const int s   = bid >> 5;     // row slice 0..7
    const int g   = bid & 31;     // batch group 0..31
    const int c0  = g * 2;        // first batch of this group
    const int tid = threadIdx.x;
    const int w   = tid >> 6;     // wave 0..7 -> 64-wide k-slice
    const int l   = tid & 63;     // lane

    __shared__ float hst[2][HH];        // [batch][k], wave-private slices (4 KB)
    __shared__ float red[2][8][4][64];  // [parity][wave][pf0,pf1,pn0,pn1][lane] (16 KB)

    // --- persistent W: row s*64+l, k-cols [64w, 64w+64), gates f and n ---
    float Wf[64], Wn[64];
    {
        const float* pf = &Whh[(size_t)(s * 64 + l) * HH + w * 64];
        const float* pn = &Whh[(size_t)(512 + s * 64 + l) * HH + w * 64];
        #pragma unroll
        for (int q = 0; q < 16; ++q) {
            float4 a = *(const float4*)&pf[q * 4];
            Wf[q*4+0] = a.x; Wf[q*4+1] = a.y; Wf[q*4+2] = a.z; Wf[q*4+3] = a.w;
            float4 b = *(const float4*)&pn[q * 4];
            Wn[q*4+0] = b.x; Wn[q*4+1] = b.y; Wn[q*4+2] = b.z; Wn[q*4+3] = b.w;
        }
    }
    asm volatile("" : P8(Wf,0),  P8(Wf,8),  P8(Wf,16), P8(Wf,24));
    asm volatile("" : P8(Wf,32), P8(Wf,40), P8(Wf,48), P8(Wf,56));
    asm volatile("" : P8(Wn,0),  P8(Wn,8),  P8(Wn,16), P8(Wn,24));
    asm volatile("" : P8(Wn,32), P8(Wn,40), P8(Wn,48), P8(Wn,56));

    // epilogue role: wave 0 -> batch c0, wave 1 -> batch c0+1; lane l -> row s*64+l
    const bool epi = (w < 2);
    float bfv = 0.f, bnv = 0.f, hprev = 0.f, in_cur = 0.f, in_nxt = 0.f;
    size_t obase = 0;
    if (epi) {
        bfv = bhh[s * 64 + l];
        bnv = bhh[512 + s * 64 + l];
        obase = (size_t)(c0 + w) * HH + s * 64 + l;   // + t*BB*HH per step
        in_nxt = io[obase];                            // i_n for t=0
    }

    const int kb = w * 64;   // wave's k-slice base (uniform per wave)

    for (int t = 0; t < TT; ++t) {
        const int p = t & 1;

        // rotate i_n pipeline: consume in_cur, issue load for t+1 (hidden
        // under this step's poll + FMA + next step's poll)
        in_cur = in_nxt;
        if (epi && t + 1 < TT)
            in_nxt = io[obase + (size_t)(t + 1) * BB * HH];

        // ---- data-poll own k-slice of h_{t-1}: detection == data arrival ----
        float v0, v1;
        if (t > 0) {
            const int tr      = t - 1;
            const int slot_r  = tr & 3;
            const unsigned ep = (unsigned)(((tr >> 2) % 3) + 1);
            const float* b0 = &hbuf[(size_t)slot_r * BB * HH
                                    + (size_t)c0 * HH + kb + l];
            const float* b1 = b0 + HH;  // second batch
            for (;;) {
                v0 = __hip_atomic_load(b0, __ATOMIC_RELAXED, __HIP_MEMORY_SCOPE_AGENT);
                v1 = __hip_atomic_load(b1, __ATOMIC_RELAXED, __HIP_MEMORY_SCOPE_AGENT);
                bool ok = ((__float_as_uint(v0) & 3u) == ep) &&
                          ((__float_as_uint(v1) & 3u) == ep);
                if (__all(ok)) break;
            }
        } else {
            v0 = 0.f; v1 = 0.f;
        }
        hst[0][kb + l] = v0;   // wave-private slice; no barrier needed
        hst[1][kb + l] = v1;

        // ---- pipelined dot products: 256 FMA/thread ----
        float pf0 = 0.f, pf1 = 0.f, pn0 = 0.f, pn1 = 0.f;
        {
            float4 h0a = *(const float4*)&hst[0][kb];
            float4 h1a = *(const float4*)&hst[1][kb];
            #pragma unroll
            for (int q = 0; q < 16; ++q) {
                float4 h0b, h1b;
                if (q < 15) {   // prefetch next chunk while FMA'ing current
                    h0b = *(const float4*)&hst[0][kb + (q + 1) * 4];
                    h1b = *(const float4*)&hst[1][kb + (q + 1) * 4];
                }
                pf0 = fmaf(Wf[q*4+0], h0a.x, pf0); pn0 = fmaf(Wn[q*4+0], h0a.x, pn0);
                pf1 = fmaf(Wf[q*4+0], h1a.x, pf1); pn1 = fmaf(Wn[q*4+0], h1a.x, pn1);
                pf0 = fmaf(Wf[q*4+1], h0a.y, pf0); pn0 = fmaf(Wn[q*4+1], h0a.y, pn0);
                pf1 = fmaf(Wf[q*4+1], h1a.y, pf1); pn1 = fmaf(Wn[q*4+1], h1a.y, pn1);
                pf0 = fmaf(Wf[q*4+2], h0a.z, pf0); pn0 = fmaf(Wn[q*4+2], h0a.z, pn0);
                pf1 = fmaf(Wf[q*4+2], h1a.z, pf1); pn1 = fmaf(Wn[q*4+2], h1a.z, pn1);
                pf0 = fmaf(Wf[q*4+3], h0a.w, pf0); pn0 = fmaf(Wn[q*4+3], h0a.w, pn0);
                pf1 = fmaf(Wf[q*4+3], h1a.w, pf1); pn1 = fmaf(Wn[q*4+3], h1a.w, pn1);
                if ((q & 3) == 3) __builtin_amdgcn_sched_barrier(0);
                h0a = h0b; h1a = h1b;
            }
        }
        red[p][w][0][l] = pf0; red[p][w][1][l] = pf1;
        red[p][w][2][l] = pn0; red[p][w][3][l] = pn1;

        __syncthreads();   // the only intra-WG barrier per step

        // ---- epilogue: wave 0 -> batch 0, wave 1 -> batch 1 ----
        if (epi) {
            float fs = 0.f, ns = 0.f;
            #pragma unroll
            for (int ww = 0; ww < 8; ++ww) {
                fs += red[p][ww][0 + w][l];
                ns += red[p][ww][2 + w][l];
            }
            // sigmoid / tanh via native exp (saturation-safe, r8-validated)
            float fg = __builtin_amdgcn_rcpf(1.f + __expf(-(fs + bfv)));
            float e2 = __expf(2.f * (in_cur + fg * (ns + bnv)));
            float nv = 1.f - 2.f * __builtin_amdgcn_rcpf(e2 + 1.f);
            float hn = nv + (1.f - fg) * (hprev - nv);
            hprev = hn;

            // publish epoch-encoded h FIRST (critical path), io after
            const unsigned ep = (unsigned)(((t >> 2) % 3) + 1);
            float ev = __uint_as_float((__float_as_uint(hn) & ~3u) | ep);
            float* dst = &hbuf[(size_t)(t & 3) * BB * HH
                               + (size_t)(c0 + w) * HH + s * 64 + l];
            __hip_atomic_store(dst, ev, __ATOMIC_RELAXED, __HIP_MEMORY_SCOPE_AGENT);
            io[obase + (size_t)t * BB * HH] = hn;
        }
        // no trailing barrier: hst is wave-private, red is parity-buffered
    }
}

// ---------------------------------------------------------------------------
extern "C" void kernel_launch(void* const* d_in, const int* in_sizes, int n_in,
                              void* d_out, int out_size, void* d_ws, size_t ws_size,
                              hipStream_t stream)
{
    const float* x   = (const float*)d_in[0];
    const float* Wih = (const float*)d_in[1];
    const float* Whh = (const float*)d_in[2];
    const float* bih = (const float*)d_in[3];
    const float* bhh = (const float*)d_in[4];
    float* io = (float*)d_out;

    float* hbuf = (float*)d_ws;   // 4 slots x 64 batches x 512 f32 = 512 KB

    // zero the slot ring: epoch bits 0 never match live epochs {1,2,3};
    // re-runs every launch/replay -> deterministic.
    hipMemsetAsync(d_ws, 0, 4 * BB * HH * 4, stream);

    in_gemm<<<dim3(16384), dim3(256), 0, stream>>>(x, Wih, bih, io);
    mgu_rec<<<dim3(256), dim3(512), 0, stream>>>(Whh, bhh, io, hbuf);
}